// Round 6
// baseline (161.866 us; speedup 1.0000x reference)
//
#include <hip/hip_runtime.h>
#include <hip/hip_bf16.h>

// Decoder: preds[s,b] = hidden[s,b,:] @ W[0] + b[0]  (S=4096, B=64, H=256)
// loss = sum((preds - outputs.T)^2); d_out = [loss, preds.reshape(-1)]
//
// Memory-bound: hidden = 256 MiB f32 read once -> read floor ~38-44 us.
// R5 = R3 two-kernel structure (NO memset node: R4 proved a 4-byte fill
// node costs ~7 us on the replay path) + 8-lane row groups:
//   - 8 rows per wave-iteration (8 KiB), 3-step xor reduce + 1 gather
//     per 8 rows -> cross-lane ops per wave drop 40 -> 16.
//   - blocked column ownership (R2: interleaved regressed).

constexpr int S = 4096;
constexpr int B = 64;
constexpr int H = 256;
constexpr int P = S * B;            // 262144 rows
constexpr int BLOCK = 256;          // 4 waves/block
constexpr int GRID = 2048;          // 8192 waves * 32 rows/wave = P exactly
constexpr int NBLK = GRID;

__global__ __launch_bounds__(BLOCK, 4) void decoder_main(
    const float* __restrict__ outputs,   // [B, S]
    const float* __restrict__ hidden,    // [S, B, H]
    const float* __restrict__ W,         // [1, H]
    const float* __restrict__ bias,     // [1]
    float* __restrict__ out,             // [1 + P]; we write out[1..P]
    float* __restrict__ ws)              // [NBLK] per-block loss partials
{
    const int tid  = threadIdx.x;
    const int lane = tid & 63;
    const int sub  = lane >> 3;          // row subgroup (0..7)
    const int l8   = lane & 7;           // lane within 8-lane row group
    const int gwave = (blockIdx.x * BLOCK + tid) >> 6;   // 0..8191
    const int base  = gwave * 32;        // this wave's 32 consecutive rows

    // Blocked W ownership: lane owns cols [l8*32, l8*32+32) = 8 float4s.
    const float4* W4 = reinterpret_cast<const float4*>(W) + l8 * 8;
    float4 w[8];
    #pragma unroll
    for (int k = 0; k < 8; ++k) w[k] = W4[k];
    const float b0 = bias[0];

    // Lane L (<32) ends holding the dot for row base+L:
    // produced at iteration t = L>>3 by subgroup L&7.
    const int tsel = lane >> 3;          // matches t only for lanes 0..31
    const int gsel = (lane & 7) << 3;    // a lane inside subgroup (L&7)

    float my_dot = 0.0f;

    #pragma unroll
    for (int t = 0; t < 4; ++t) {
        const int p = base + 8 * t + sub;
        const float4* hp =
            reinterpret_cast<const float4*>(hidden + (size_t)p * H) + l8 * 8;
        float4 h[8];
        #pragma unroll
        for (int k = 0; k < 8; ++k) h[k] = hp[k];

        float d = 0.0f;
        #pragma unroll
        for (int k = 0; k < 8; ++k)
            d += h[k].x * w[k].x + h[k].y * w[k].y +
                 h[k].z * w[k].z + h[k].w * w[k].w;

        // Reduce within each 8-lane group (xor 1,2,4 stays within group).
        #pragma unroll
        for (int off = 1; off < 8; off <<= 1)
            d += __shfl_xor(d, off, 64);

        // Gather: lane L grabs subgroup (L&7)'s dot; keeps it if t == L>>3.
        const float g = __shfl(d, gsel, 64);
        if (t == tsel) my_dot = g;
    }

    // Epilogue: coalesced pred store + loss contribution (lanes 0..31).
    float se = 0.0f;
    if (lane < 32) {
        const float pred = my_dot + b0;
        out[1 + base + lane] = pred;               // 128B contiguous store
        const int s_idx = base >> 6;               // same s for all 32 rows
        const int bb    = (base & 63) + lane;      // bb in [0,64)
        const float diff = pred - outputs[bb * S + s_idx];  // L2-resident
        se = diff * diff;
    }

    // Wave then block reduce of squared-error partials; one store per block.
    #pragma unroll
    for (int off = 32; off > 0; off >>= 1)
        se += __shfl_xor(se, off, 64);

    __shared__ float lsum[BLOCK / 64];
    if (lane == 0) lsum[tid >> 6] = se;
    __syncthreads();
    if (tid == 0) ws[blockIdx.x] = lsum[0] + lsum[1] + lsum[2] + lsum[3];
}

__global__ __launch_bounds__(BLOCK) void decoder_loss(
    const float* __restrict__ ws,        // [NBLK]
    float* __restrict__ out)             // out[0] = loss
{
    const int tid = threadIdx.x;
    float s = 0.0f;
    #pragma unroll
    for (int i = 0; i < NBLK / BLOCK; ++i)   // 8 coalesced passes
        s += ws[tid + BLOCK * i];
    #pragma unroll
    for (int off = 32; off > 0; off >>= 1)
        s += __shfl_xor(s, off, 64);
    __shared__ float lsum[BLOCK / 64];
    if ((tid & 63) == 0) lsum[tid >> 6] = s;
    __syncthreads();
    if (tid == 0) out[0] = lsum[0] + lsum[1] + lsum[2] + lsum[3];
}

extern "C" void kernel_launch(void* const* d_in, const int* in_sizes, int n_in,
                              void* d_out, int out_size, void* d_ws, size_t ws_size,
                              hipStream_t stream) {
    const float* outputs = (const float*)d_in[0];  // [B, S]
    const float* hidden  = (const float*)d_in[1];  // [S, B, H]
    const float* W       = (const float*)d_in[2];  // [1, H]
    const float* bias    = (const float*)d_in[3];  // [1]
    float* out = (float*)d_out;                    // [1 + S*B]
    float* ws  = (float*)d_ws;                     // >= NBLK floats

    decoder_main<<<GRID, BLOCK, 0, stream>>>(outputs, hidden, W, bias, out, ws);
    decoder_loss<<<1, BLOCK, 0, stream>>>(ws, out);
}

// Round 7
// 47.344 us; speedup vs baseline: 3.4190x; 3.4190x over previous
//
#include <hip/hip_runtime.h>
#include <hip/hip_bf16.h>

// Decoder: preds[s,b] = hidden[s,b,:] @ W[0] + b[0]  (S=4096, B=64, H=256)
// loss = sum((preds - outputs.T)^2); d_out = [loss, preds.reshape(-1)]
//
// Memory-bound: hidden = 256 MiB f32 read once -> read floor ~40 us.
// R6 = R3 structure (best: 52.7 us) with finer work quanta:
//   - 64B per lane per row (4 consecutive float4s = 1 cache line) --
//     proven sweet spot (16B/lane R0 and 128B/lane R5 both lose;
//     R5's 128B/lane caused 2.15x FETCH inflation).
//   - two kernels, NO fill nodes (R4: a 4-byte memset node costs ~7 us).
//   - GRID 4096, 16 rows/wave (was 2048/32): halves tail granularity.

constexpr int S = 4096;
constexpr int B = 64;
constexpr int H = 256;
constexpr int P = S * B;            // 262144 rows
constexpr int BLOCK = 256;          // 4 waves/block
constexpr int GRID = 4096;          // 16384 waves * 16 rows/wave = P exactly
constexpr int NBLK = GRID;

__global__ __launch_bounds__(BLOCK, 4) void decoder_main(
    const float* __restrict__ outputs,   // [B, S]
    const float* __restrict__ hidden,    // [S, B, H]
    const float* __restrict__ W,         // [1, H]
    const float* __restrict__ bias,      // [1]
    float* __restrict__ out,             // [1 + P]; we write out[1..P]
    float* __restrict__ ws)              // [NBLK] per-block loss partials
{
    const int tid  = threadIdx.x;
    const int lane = tid & 63;
    const int sub  = lane >> 4;          // row subgroup (0..3)
    const int l16  = lane & 15;          // lane within 16-lane row group
    const int gwave = (blockIdx.x * BLOCK + tid) >> 6;   // 0..16383
    const int base  = gwave * 16;        // this wave's 16 consecutive rows

    // Blocked W ownership: lane owns cols [l16*16, l16*16+16) = 64B.
    const float4* W4 = reinterpret_cast<const float4*>(W) + l16 * 4;
    const float4 w0 = W4[0], w1 = W4[1], w2 = W4[2], w3 = W4[3];
    const float b0 = bias[0];

    // Lane L (<16) ends holding the dot for row base+L:
    // produced at iteration t = L>>2 by subgroup L&3.
    const int tsel = lane >> 2;          // matches t (0..3) only for lanes 0..15
    const int gsel = (lane & 3) << 4;    // a lane inside subgroup (L&3)

    float my_dot = 0.0f;

    #pragma unroll
    for (int t = 0; t < 4; ++t) {
        const int p = base + 4 * t + sub;
        const float4* hp =
            reinterpret_cast<const float4*>(hidden + (size_t)p * H) + l16 * 4;
        const float4 h0 = hp[0], h1 = hp[1], h2 = hp[2], h3 = hp[3];

        float d = h0.x * w0.x + h0.y * w0.y + h0.z * w0.z + h0.w * w0.w;
        d += h1.x * w1.x + h1.y * w1.y + h1.z * w1.z + h1.w * w1.w;
        d += h2.x * w2.x + h2.y * w2.y + h2.z * w2.z + h2.w * w2.w;
        d += h3.x * w3.x + h3.y * w3.y + h3.z * w3.z + h3.w * w3.w;

        // Reduce within each 16-lane group (xor 1,2,4,8 stays within group).
        #pragma unroll
        for (int off = 1; off < 16; off <<= 1)
            d += __shfl_xor(d, off, 64);

        // Gather: lane L grabs subgroup (L&3)'s dot; keeps it if t == L>>2.
        const float g = __shfl(d, gsel, 64);
        if (t == tsel) my_dot = g;
    }

    // Epilogue: coalesced pred store + loss contribution (lanes 0..15).
    float se = 0.0f;
    if (lane < 16) {
        const float pred = my_dot + b0;
        out[1 + base + lane] = pred;               // 64B contiguous store
        const int s_idx = base >> 6;               // same s for all 16 rows
        const int bb    = (base & 63) + lane;      // bb in [0,64)
        const float diff = pred - outputs[bb * S + s_idx];  // L2-resident
        se = diff * diff;
    }

    // Wave then block reduce of squared-error partials; one store per block.
    #pragma unroll
    for (int off = 32; off > 0; off >>= 1)
        se += __shfl_xor(se, off, 64);

    __shared__ float lsum[BLOCK / 64];
    if (lane == 0) lsum[tid >> 6] = se;
    __syncthreads();
    if (tid == 0) ws[blockIdx.x] = lsum[0] + lsum[1] + lsum[2] + lsum[3];
}

__global__ __launch_bounds__(BLOCK) void decoder_loss(
    const float* __restrict__ ws,        // [NBLK]
    float* __restrict__ out)             // out[0] = loss
{
    const int tid = threadIdx.x;
    float s = 0.0f;
    #pragma unroll
    for (int i = 0; i < NBLK / BLOCK; ++i)   // 16 coalesced passes
        s += ws[tid + BLOCK * i];
    #pragma unroll
    for (int off = 32; off > 0; off >>= 1)
        s += __shfl_xor(s, off, 64);
    __shared__ float lsum[BLOCK / 64];
    if ((tid & 63) == 0) lsum[tid >> 6] = s;
    __syncthreads();
    if (tid == 0) out[0] = lsum[0] + lsum[1] + lsum[2] + lsum[3];
}

extern "C" void kernel_launch(void* const* d_in, const int* in_sizes, int n_in,
                              void* d_out, int out_size, void* d_ws, size_t ws_size,
                              hipStream_t stream) {
    const float* outputs = (const float*)d_in[0];  // [B, S]
    const float* hidden  = (const float*)d_in[1];  // [S, B, H]
    const float* W       = (const float*)d_in[2];  // [1, H]
    const float* bias    = (const float*)d_in[3];  // [1]
    float* out = (float*)d_out;                    // [1 + S*B]
    float* ws  = (float*)d_ws;                     // >= NBLK floats

    decoder_main<<<GRID, BLOCK, 0, stream>>>(outputs, hidden, W, bias, out, ws);
    decoder_loss<<<1, BLOCK, 0, stream>>>(ws, out);
}

// Round 8
// 45.251 us; speedup vs baseline: 3.5771x; 1.0462x over previous
//
#include <hip/hip_runtime.h>
#include <hip/hip_bf16.h>

// Decoder: preds[s,b] = hidden[s,b,:] @ W[0] + b[0]  (S=4096, B=64, H=256)
// loss = sum((preds - outputs.T)^2); d_out = [loss, preds.reshape(-1)]
//
// Memory-bound: hidden = 256 MiB f32 read once -> read floor ~41 us.
// R7 = R6 with one more granularity notch (the lever that gave -5.4 us):
//   - GRID 8192, 8 rows/wave (4 scheduling generations, shorter drain tail)
//   - 64B per lane per row kept (R0 16B/lane and R5 128B/lane both lose)
//   - two kernels, NO fill nodes (R4: 4-byte memset node costs ~7 us)
//   - loss kernel reads partials as float4

constexpr int S = 4096;
constexpr int B = 64;
constexpr int H = 256;
constexpr int P = S * B;            // 262144 rows
constexpr int BLOCK = 256;          // 4 waves/block
constexpr int GRID = 8192;          // 32768 waves * 8 rows/wave = P exactly
constexpr int NBLK = GRID;          // 32 KB of partials in d_ws

__global__ __launch_bounds__(BLOCK, 4) void decoder_main(
    const float* __restrict__ outputs,   // [B, S]
    const float* __restrict__ hidden,    // [S, B, H]
    const float* __restrict__ W,         // [1, H]
    const float* __restrict__ bias,      // [1]
    float* __restrict__ out,             // [1 + P]; we write out[1..P]
    float* __restrict__ ws)              // [NBLK] per-block loss partials
{
    const int tid  = threadIdx.x;
    const int lane = tid & 63;
    const int sub  = lane >> 4;          // row subgroup (0..3)
    const int l16  = lane & 15;          // lane within 16-lane row group
    const int gwave = (blockIdx.x * BLOCK + tid) >> 6;   // 0..32767
    const int base  = gwave * 8;         // this wave's 8 consecutive rows

    // Blocked W ownership: lane owns cols [l16*16, l16*16+16) = 64B.
    const float4* W4 = reinterpret_cast<const float4*>(W) + l16 * 4;
    const float4 w0 = W4[0], w1 = W4[1], w2 = W4[2], w3 = W4[3];
    const float b0 = bias[0];

    // Lane L (<8) ends holding the dot for row base+L:
    // produced at iteration t = L>>2 by subgroup L&3.
    const int tsel = lane >> 2;          // matches t (0..1) only for lanes 0..7
    const int gsel = (lane & 3) << 4;    // a lane inside subgroup (L&3)

    float my_dot = 0.0f;

    #pragma unroll
    for (int t = 0; t < 2; ++t) {
        const int p = base + 4 * t + sub;
        const float4* hp =
            reinterpret_cast<const float4*>(hidden + (size_t)p * H) + l16 * 4;
        const float4 h0 = hp[0], h1 = hp[1], h2 = hp[2], h3 = hp[3];

        float d = h0.x * w0.x + h0.y * w0.y + h0.z * w0.z + h0.w * w0.w;
        d += h1.x * w1.x + h1.y * w1.y + h1.z * w1.z + h1.w * w1.w;
        d += h2.x * w2.x + h2.y * w2.y + h2.z * w2.z + h2.w * w2.w;
        d += h3.x * w3.x + h3.y * w3.y + h3.z * w3.z + h3.w * w3.w;

        // Reduce within each 16-lane group (xor 1,2,4,8 stays within group).
        #pragma unroll
        for (int off = 1; off < 16; off <<= 1)
            d += __shfl_xor(d, off, 64);

        // Gather: lane L grabs subgroup (L&3)'s dot; keeps it if t == L>>2.
        const float g = __shfl(d, gsel, 64);
        if (t == tsel) my_dot = g;
    }

    // Epilogue: coalesced pred store + loss contribution (lanes 0..7).
    float se = 0.0f;
    if (lane < 8) {
        const float pred = my_dot + b0;
        out[1 + base + lane] = pred;               // 32B contiguous store
        const int s_idx = base >> 6;               // same s for all 8 rows
        const int bb    = (base & 63) + lane;      // bb in [0,64)
        const float diff = pred - outputs[bb * S + s_idx];  // L2-resident
        se = diff * diff;
    }

    // Wave then block reduce of squared-error partials; one store per block.
    #pragma unroll
    for (int off = 32; off > 0; off >>= 1)
        se += __shfl_xor(se, off, 64);

    __shared__ float lsum[BLOCK / 64];
    if (lane == 0) lsum[tid >> 6] = se;
    __syncthreads();
    if (tid == 0) ws[blockIdx.x] = lsum[0] + lsum[1] + lsum[2] + lsum[3];
}

__global__ __launch_bounds__(BLOCK) void decoder_loss(
    const float* __restrict__ ws,        // [NBLK]
    float* __restrict__ out)             // out[0] = loss
{
    const int tid = threadIdx.x;
    const float4* w4 = reinterpret_cast<const float4*>(ws);
    float s = 0.0f;
    #pragma unroll
    for (int i = 0; i < NBLK / (BLOCK * 4); ++i) {   // 8 float4 passes
        const float4 v = w4[tid + BLOCK * i];
        s += v.x + v.y + v.z + v.w;
    }
    #pragma unroll
    for (int off = 32; off > 0; off >>= 1)
        s += __shfl_xor(s, off, 64);
    __shared__ float lsum[BLOCK / 64];
    if ((tid & 63) == 0) lsum[tid >> 6] = s;
    __syncthreads();
    if (tid == 0) out[0] = lsum[0] + lsum[1] + lsum[2] + lsum[3];
}

extern "C" void kernel_launch(void* const* d_in, const int* in_sizes, int n_in,
                              void* d_out, int out_size, void* d_ws, size_t ws_size,
                              hipStream_t stream) {
    const float* outputs = (const float*)d_in[0];  // [B, S]
    const float* hidden  = (const float*)d_in[1];  // [S, B, H]
    const float* W       = (const float*)d_in[2];  // [1, H]
    const float* bias    = (const float*)d_in[3];  // [1]
    float* out = (float*)d_out;                    // [1 + S*B]
    float* ws  = (float*)d_ws;                     // >= NBLK*4 bytes

    decoder_main<<<GRID, BLOCK, 0, stream>>>(outputs, hidden, W, bias, out, ws);
    decoder_loss<<<1, BLOCK, 0, stream>>>(ws, out);
}

// Round 9
// 44.797 us; speedup vs baseline: 3.6133x; 1.0101x over previous
//
#include <hip/hip_runtime.h>
#include <hip/hip_bf16.h>

// Decoder: preds[s,b] = hidden[s,b,:] @ W[0] + b[0]  (S=4096, B=64, H=256)
// loss = sum((preds - outputs.T)^2); d_out = [loss, preds.reshape(-1)]
//
// Memory-bound: hidden = 256 MiB f32 read once -> read floor ~41 us.
// R8 = R7 with one more granularity notch (granularity paid in R6 and R7):
//   - GRID 16384, 4 rows/wave: ONE load iteration per wave, no t-loop,
//     one gather shuffle. 8 scheduling generations, minimal drain tail.
//   - 64B per lane per row kept (R0 16B/lane and R5 128B/lane both lose)
//   - two kernels, NO fill nodes (R4: 4-byte memset node costs ~7 us)

constexpr int S = 4096;
constexpr int B = 64;
constexpr int H = 256;
constexpr int P = S * B;            // 262144 rows
constexpr int BLOCK = 256;          // 4 waves/block
constexpr int GRID = 16384;         // 65536 waves * 4 rows/wave = P exactly
constexpr int NBLK = GRID;          // 64 KB of partials in d_ws

__global__ __launch_bounds__(BLOCK, 4) void decoder_main(
    const float* __restrict__ outputs,   // [B, S]
    const float* __restrict__ hidden,    // [S, B, H]
    const float* __restrict__ W,         // [1, H]
    const float* __restrict__ bias,      // [1]
    float* __restrict__ out,             // [1 + P]; we write out[1..P]
    float* __restrict__ ws)              // [NBLK] per-block loss partials
{
    const int tid  = threadIdx.x;
    const int lane = tid & 63;
    const int sub  = lane >> 4;          // row subgroup (0..3)
    const int l16  = lane & 15;          // lane within 16-lane row group
    const int gwave = (blockIdx.x * BLOCK + tid) >> 6;   // 0..65535
    const int base  = gwave * 4;         // this wave's 4 consecutive rows

    // Blocked W ownership: lane owns cols [l16*16, l16*16+16) = 64B.
    const float4* W4 = reinterpret_cast<const float4*>(W) + l16 * 4;
    const float4 w0 = W4[0], w1 = W4[1], w2 = W4[2], w3 = W4[3];
    const float b0 = bias[0];

    // Single iteration: 4 rows, one 64B load per lane.
    const int p = base + sub;
    const float4* hp =
        reinterpret_cast<const float4*>(hidden + (size_t)p * H) + l16 * 4;
    const float4 h0 = hp[0], h1 = hp[1], h2 = hp[2], h3 = hp[3];

    float d = h0.x * w0.x + h0.y * w0.y + h0.z * w0.z + h0.w * w0.w;
    d += h1.x * w1.x + h1.y * w1.y + h1.z * w1.z + h1.w * w1.w;
    d += h2.x * w2.x + h2.y * w2.y + h2.z * w2.z + h2.w * w2.w;
    d += h3.x * w3.x + h3.y * w3.y + h3.z * w3.z + h3.w * w3.w;

    // Reduce within each 16-lane group (xor 1,2,4,8 stays within group).
    #pragma unroll
    for (int off = 1; off < 16; off <<= 1)
        d += __shfl_xor(d, off, 64);

    // Lane L (<4) grabs subgroup L's dot (broadcast within group).
    const float my_dot = __shfl(d, (lane & 3) << 4, 64);

    // Epilogue: coalesced pred store + loss contribution (lanes 0..3).
    float se = 0.0f;
    if (lane < 4) {
        const float pred = my_dot + b0;
        out[1 + base + lane] = pred;               // 16B contiguous store
        const int s_idx = base >> 6;               // same s for all 4 rows
        const int bb    = (base & 63) + lane;      // bb in [0,64)
        const float diff = pred - outputs[bb * S + s_idx];  // L2-resident
        se = diff * diff;
    }

    // Wave then block reduce of squared-error partials; one store per block.
    #pragma unroll
    for (int off = 32; off > 0; off >>= 1)
        se += __shfl_xor(se, off, 64);

    __shared__ float lsum[BLOCK / 64];
    if (lane == 0) lsum[tid >> 6] = se;
    __syncthreads();
    if (tid == 0) ws[blockIdx.x] = lsum[0] + lsum[1] + lsum[2] + lsum[3];
}

__global__ __launch_bounds__(BLOCK) void decoder_loss(
    const float* __restrict__ ws,        // [NBLK]
    float* __restrict__ out)             // out[0] = loss
{
    const int tid = threadIdx.x;
    const float4* w4 = reinterpret_cast<const float4*>(ws);
    float s = 0.0f;
    #pragma unroll
    for (int i = 0; i < NBLK / (BLOCK * 4); ++i) {   // 16 float4 passes
        const float4 v = w4[tid + BLOCK * i];
        s += v.x + v.y + v.z + v.w;
    }
    #pragma unroll
    for (int off = 32; off > 0; off >>= 1)
        s += __shfl_xor(s, off, 64);
    __shared__ float lsum[BLOCK / 64];
    if ((tid & 63) == 0) lsum[tid >> 6] = s;
    __syncthreads();
    if (tid == 0) out[0] = lsum[0] + lsum[1] + lsum[2] + lsum[3];
}

extern "C" void kernel_launch(void* const* d_in, const int* in_sizes, int n_in,
                              void* d_out, int out_size, void* d_ws, size_t ws_size,
                              hipStream_t stream) {
    const float* outputs = (const float*)d_in[0];  // [B, S]
    const float* hidden  = (const float*)d_in[1];  // [S, B, H]
    const float* W       = (const float*)d_in[2];  // [1, H]
    const float* bias    = (const float*)d_in[3];  // [1]
    float* out = (float*)d_out;                    // [1 + S*B]
    float* ws  = (float*)d_ws;                     // >= NBLK*4 bytes

    decoder_main<<<GRID, BLOCK, 0, stream>>>(outputs, hidden, W, bias, out, ws);
    decoder_loss<<<1, BLOCK, 0, stream>>>(ws, out);
}